// Round 1
// baseline (137.417 us; speedup 1.0000x reference)
//
#include <hip/hip_runtime.h>

// Problem constants (fixed by setup_inputs in the reference).
#define BB 128
#define CC 3
#define HH 224
#define WW 224
#define PP 16

#define W4 (WW / 4)               // 56 float4 per row
#define CHAN4 (HH * W4)           // 12544 float4 per channel = 49 * 256 (exact)
#define PER_IMG4 (CC * CHAN4)     // 37632 float4 per image
#define NBLK (BB * (CHAN4 / 256)) // 128 * 49 = 6272 blocks

// Global mask layout: one bit per pixel, row-major, 8 words per row
// (224 bits -> 7 words used, padded to 8 for cheap indexing).
#define MROW 8
#define MIMG (HH * MROW)                      // 1792 words per image
#define MASK_BYTES ((size_t)BB * MIMG * 4)    // 917504 B

typedef float vfloat4 __attribute__((ext_vector_type(4)));

// ---------------------------------------------------------------------------
// Kernel A: one block per image builds the full 224-row occlusion bitmask in
// LDS (all 256 threads cooperate over the 98x16 (point,row) pairs), then dumps
// it to global workspace. This hoists ALL mask work out of the streaming
// kernel: previously each image's point list was re-clipped 49x (once per
// 256-position block), serialized behind LDS atomics + 2 barriers on the
// critical path of every global load.
// ---------------------------------------------------------------------------
__global__ __launch_bounds__(256) void build_masks(
        unsigned int* __restrict__ masks, const int* __restrict__ px,
        const int* __restrict__ py, int N) {
    const int b = blockIdx.x;
    const int t = threadIdx.x;

    __shared__ unsigned int rb[MIMG];   // 7168 B
    __shared__ int sx[128], sy[128];

    for (int i = t; i < MIMG; i += 256) rb[i] = 0u;
    if (t < N) { sx[t] = px[b * N + t]; sy[t] = py[b * N + t]; }
    __syncthreads();

    // One (point, patch-row) pair per iteration: N*PP = 1568 pairs.
    for (int idx = t; idx < N * PP; idx += 256) {
        const int pt = idx >> 4;        // PP == 16
        const int r  = idx & (PP - 1);
        const int x  = sx[pt] + r;      // image row, <= 208+15 = 223
        const int y  = sy[pt];          // first column of the 16-wide span
        unsigned long long mm = 0xFFFFull << (y & 31);
        const int w = y >> 5;
        atomicOr(&rb[x * MROW + w], (unsigned int)mm);
        const unsigned int hi = (unsigned int)(mm >> 32);
        if (hi) atomicOr(&rb[x * MROW + w + 1], hi);
    }
    __syncthreads();

    for (int i = t; i < MIMG; i += 256) masks[b * MIMG + i] = rb[i];
}

// ---------------------------------------------------------------------------
// Kernel B: pure streaming. No LDS, no atomics, no barriers -- every resident
// wave feeds the memory pipe for its entire lifetime. Mask word is an L2-hot
// load shared by 8 consecutive lanes. Fully-masked float4s skip the global
// load (exec-masked lanes -> HW coalescer drops dead cache lines).
// ---------------------------------------------------------------------------
__global__ __launch_bounds__(256) void occl_apply(
        vfloat4* __restrict__ out, const vfloat4* __restrict__ imgs,
        const unsigned int* __restrict__ masks) {
    const int t = threadIdx.x;
    const int b = blockIdx.x / (CHAN4 / 256);        // image index
    const int p = (blockIdx.x % (CHAN4 / 256)) * 256 + t;  // pos in channel
    const int w4 = p % W4;
    const int h  = p / W4;

    const unsigned int word = masks[b * MIMG + h * MROW + (w4 >> 3)];
    const unsigned int m4 = (word >> ((w4 & 7) * 4)) & 0xFu;

    const size_t f0 = (size_t)b * PER_IMG4 + p;      // channel 0
    vfloat4 z = {0.f, 0.f, 0.f, 0.f};
    vfloat4 v0 = z, v1 = z, v2 = z;
    if (m4 != 0xFu) {                 // skip loads where all 4 px masked
        v0 = __builtin_nontemporal_load(&imgs[f0]);
        v1 = __builtin_nontemporal_load(&imgs[f0 + CHAN4]);
        v2 = __builtin_nontemporal_load(&imgs[f0 + 2 * CHAN4]);
        if (m4 & 1u) { v0.x = 0.f; v1.x = 0.f; v2.x = 0.f; }
        if (m4 & 2u) { v0.y = 0.f; v1.y = 0.f; v2.y = 0.f; }
        if (m4 & 4u) { v0.z = 0.f; v1.z = 0.f; v2.z = 0.f; }
        if (m4 & 8u) { v0.w = 0.f; v1.w = 0.f; v2.w = 0.f; }
    }
    __builtin_nontemporal_store(v0, &out[f0]);
    __builtin_nontemporal_store(v1, &out[f0 + CHAN4]);
    __builtin_nontemporal_store(v2, &out[f0 + 2 * CHAN4]);
}

// ---------------------------------------------------------------------------
// Fallback (previous best): channel-fused single kernel with per-block 6-row
// mask build. Used only if the workspace is too small for the global mask.
// ---------------------------------------------------------------------------
#define NROWS 6
__global__ __launch_bounds__(256) void occl_fused(
        vfloat4* __restrict__ out, const vfloat4* __restrict__ imgs,
        const int* __restrict__ px, const int* __restrict__ py, int N) {
    const int t     = threadIdx.x;
    const int b     = blockIdx.x / (CHAN4 / 256);
    const int posF0 = (blockIdx.x % (CHAN4 / 256)) * 256;
    const int h0    = posF0 / W4;

    __shared__ unsigned int rowbits[NROWS * 7];
    if (t < NROWS * 7) rowbits[t] = 0u;
    __syncthreads();

    if (t < N) {
        int x = px[b * N + t];
        int y = py[b * N + t];
        int lo = x > h0 ? x : h0;
        int hi = (x + PP < h0 + NROWS) ? (x + PP) : (h0 + NROWS);
        if (lo < hi) {
            unsigned long long mm = 0xFFFFull << (y & 31);
            unsigned int lo32 = (unsigned int)mm;
            unsigned int hi32 = (unsigned int)(mm >> 32);
            int woff = y >> 5;
            for (int h = lo; h < hi; ++h) {
                int base = (h - h0) * 7 + woff;
                atomicOr(&rowbits[base], lo32);
                if (hi32) atomicOr(&rowbits[base + 1], hi32);
            }
        }
    }
    __syncthreads();

    int p  = posF0 + t;
    int w4 = p % W4;
    int h  = p / W4;
    unsigned int word = rowbits[(h - h0) * 7 + (w4 >> 3)];
    unsigned int m4 = (word >> ((w4 & 7) * 4)) & 0xFu;

    size_t f0 = (size_t)b * PER_IMG4 + p;
    vfloat4 z = {0.f, 0.f, 0.f, 0.f};
    vfloat4 v0 = z, v1 = z, v2 = z;
    if (m4 != 0xFu) {
        v0 = __builtin_nontemporal_load(&imgs[f0]);
        v1 = __builtin_nontemporal_load(&imgs[f0 + CHAN4]);
        v2 = __builtin_nontemporal_load(&imgs[f0 + 2 * CHAN4]);
        if (m4 & 1u) { v0.x = 0.f; v1.x = 0.f; v2.x = 0.f; }
        if (m4 & 2u) { v0.y = 0.f; v1.y = 0.f; v2.y = 0.f; }
        if (m4 & 4u) { v0.z = 0.f; v1.z = 0.f; v2.z = 0.f; }
        if (m4 & 8u) { v0.w = 0.f; v1.w = 0.f; v2.w = 0.f; }
    }
    __builtin_nontemporal_store(v0, &out[f0]);
    __builtin_nontemporal_store(v1, &out[f0 + CHAN4]);
    __builtin_nontemporal_store(v2, &out[f0 + 2 * CHAN4]);
}

extern "C" void kernel_launch(void* const* d_in, const int* in_sizes, int n_in,
                              void* d_out, int out_size, void* d_ws, size_t ws_size,
                              hipStream_t stream) {
    const float* imgs = (const float*)d_in[0];
    const int*   px   = (const int*)d_in[1];
    const int*   py   = (const int*)d_in[2];
    float*       out  = (float*)d_out;

    const int N = in_sizes[1] / BB;  // points per image (98)

    if (ws_size >= MASK_BYTES && d_ws != nullptr) {
        unsigned int* masks = (unsigned int*)d_ws;
        build_masks<<<BB, 256, 0, stream>>>(masks, px, py, N);
        occl_apply<<<NBLK, 256, 0, stream>>>(
            (vfloat4*)out, (const vfloat4*)imgs, masks);
    } else {
        occl_fused<<<NBLK, 256, 0, stream>>>(
            (vfloat4*)out, (const vfloat4*)imgs, px, py, N);
    }
}